// Round 8
// baseline (50.036 us; speedup 1.0000x reference)
//
#include <hip/hip_runtime.h>

#define HH 128
#define TAB_N 4096
#define TAB_LO (-8.0f)
#define TAB_HI (8.0f)
#define NBLK 512

// ws layout: [0,16KB) table | [16KB, 16KB+128KB) partial[NBLK][64] | counter

// ---------------------------------------------------------------------------
// Kernel A (register-resident W2): tabulate
//   y(u) = W3^T relu(W2^T relu(u*w1+b1) + b2) + b3
// on TAB_N uniform grid points, exact fp32. 256 blocks x 256 threads; block
// handles 16 consecutive entries. Thread (c = tid&31, ig = tid>>5) owns W2
// rows 16ig..16ig+15, cols 4c..4c+3 in registers. Phase 1 all-register FMA;
// phase 2 one LDS round trip + 16-lane shfl reduce -> table entry.
// Block 0 thread 0 zeroes the completion counter for kernel B (visible to
// B's coherent-point RMWs via A's end-of-kernel release).
// ---------------------------------------------------------------------------
__global__ __launch_bounds__(256) void build_table_kernel(
    const float* __restrict__ W1, const float* __restrict__ b1,
    const float* __restrict__ W2, const float* __restrict__ b2,
    const float* __restrict__ W3, const float* __restrict__ b3,
    float* __restrict__ table, int* __restrict__ counter)
{
    __shared__ float4 lds4[16 * 8 * 32];  // [entry][ig][c] = 64 KiB
    const int tid = threadIdx.x;
    const int c  = tid & 31;   // col-group: cols 4c..4c+3
    const int ig = tid >> 5;   // row-group: rows 16ig..16ig+15

    if (blockIdx.x == 0 && tid == 0) *counter = 0;

    // --- load register tiles ---
    float4 w2r[16];
    const float4* W2v = reinterpret_cast<const float4*>(W2);
#pragma unroll
    for (int r = 0; r < 16; ++r)
        w2r[r] = W2v[(16 * ig + r) * 32 + c];   // W2[row][4c..4c+3]

    float w1r[16], b1r[16];
#pragma unroll
    for (int r = 0; r < 16; ++r) {
        w1r[r] = W1[16 * ig + r];
        b1r[r] = b1[16 * ig + r];
    }

    const float step = (TAB_HI - TAB_LO) / (float)(TAB_N - 1);
    const int e0 = blockIdx.x * 16;

    // --- phase 1: all-register FMA for the block's 16 entries ---
    float4 facc[16];
#pragma unroll
    for (int e = 0; e < 16; ++e) {
        const float u = TAB_LO + step * (float)(e0 + e);
        float4 a = make_float4(0.f, 0.f, 0.f, 0.f);
#pragma unroll
        for (int r = 0; r < 16; ++r) {
            const float h1 = fmaxf(fmaf(u, w1r[r], b1r[r]), 0.0f);
            a.x = fmaf(h1, w2r[r].x, a.x);
            a.y = fmaf(h1, w2r[r].y, a.y);
            a.z = fmaf(h1, w2r[r].z, a.z);
            a.w = fmaf(h1, w2r[r].w, a.w);
        }
        facc[e] = a;
    }

    // --- phase 2: single LDS round trip + reduce ---
#pragma unroll
    for (int e = 0; e < 16; ++e)
        lds4[(e * 8 + ig) * 32 + c] = facc[e];
    __syncthreads();

    // 512 (entry, col-group) cells; 2 per thread. cell = 2*tid+t:
    //   e = cell>>5 = tid>>4,  c2 = cell&31 = 2*(tid&15)+t
    const float4* b2v = reinterpret_cast<const float4*>(b2);
    const float4* W3v = reinterpret_cast<const float4*>(W3);
    float part = 0.0f;
#pragma unroll
    for (int t = 0; t < 2; ++t) {
        const int cell = 2 * tid + t;
        const int e  = cell >> 5;
        const int c2 = cell & 31;
        float4 s = make_float4(0.f, 0.f, 0.f, 0.f);
#pragma unroll
        for (int m = 0; m < 8; ++m) {
            const float4 v = lds4[(e * 8 + m) * 32 + c2];
            s.x += v.x; s.y += v.y; s.z += v.z; s.w += v.w;
        }
        const float4 bb = b2v[c2];
        const float4 ww = W3v[c2];
        float v = 0.0f;
        v += fmaxf(s.x + bb.x, 0.f) * ww.x;
        v += fmaxf(s.y + bb.y, 0.f) * ww.y;
        v += fmaxf(s.z + bb.z, 0.f) * ww.z;
        v += fmaxf(s.w + bb.w, 0.f) * ww.w;
        part += v;
    }
    // threads tid = 16e..16e+15 hold entry e's 32 col-group partials
    part += __shfl_xor(part, 1, 16);
    part += __shfl_xor(part, 2, 16);
    part += __shfl_xor(part, 4, 16);
    part += __shfl_xor(part, 8, 16);
    if ((tid & 15) == 0)
        table[e0 + (tid >> 4)] = part + b3[0];
}

// ---------------------------------------------------------------------------
// Kernel B: stream U as float4 (unroll x4), nearest-neighbor y(u) from
// 16 KiB LDS table, block-reduce in LDS, then publish 64 partials via
// AGENT-SCOPE RELAXED ATOMIC STORES (bypass non-coherent L2s; fire-and-
// forget, no fences). __syncthreads() drains vmcnt(0) -> stores complete at
// the coherent point before the single int fetch_add per block. The last
// block reads all partials with agent-scope atomic loads (immune to stale
// L2 lines from the previous graph replay), reduces in a FIXED order, and
// writes out[64]. Deterministic; no fp32 atomics, no threadfence.
// ---------------------------------------------------------------------------
__global__ __launch_bounds__(256) void mlp_mean_kernel(
    const float4* __restrict__ U4, const float* __restrict__ table,
    float* __restrict__ partial, int* __restrict__ counter,
    float* __restrict__ out, int nf4, float inv_n)
{
    __shared__ float tabs[TAB_N];   // 16 KiB
    __shared__ float4 red[256];     // 4 KiB
    __shared__ int lastflag;
    const int tid = threadIdx.x;

    {
        const float4* tv = reinterpret_cast<const float4*>(table);
        float4* t4 = reinterpret_cast<float4*>(tabs);
#pragma unroll
        for (int j = 0; j < (TAB_N / 4) / 256; ++j)
            t4[tid + 256 * j] = tv[tid + 256 * j];
    }
    __syncthreads();

    const float step = (TAB_HI - TAB_LO) / (float)(TAB_N - 1);
    const float scale = 1.0f / step;
    const float bias = 0.5f - TAB_LO * scale;
    const float tmax = (float)(TAB_N - 1) + 0.49f;

    float4 acc = make_float4(0.f, 0.f, 0.f, 0.f);
    auto accum = [&](float4 v) {
        float t0 = fminf(fmaxf(fmaf(v.x, scale, bias), 0.f), tmax);
        float t1 = fminf(fmaxf(fmaf(v.y, scale, bias), 0.f), tmax);
        float t2 = fminf(fmaxf(fmaf(v.z, scale, bias), 0.f), tmax);
        float t3 = fminf(fmaxf(fmaf(v.w, scale, bias), 0.f), tmax);
        acc.x += tabs[(int)t0];
        acc.y += tabs[(int)t1];
        acc.z += tabs[(int)t2];
        acc.w += tabs[(int)t3];
    };

    const int stride = NBLK * 256;
    int f = blockIdx.x * 256 + tid;
    for (; f + 3 * stride < nf4; f += 4 * stride) {
        float4 v0 = U4[f];
        float4 v1 = U4[f + stride];
        float4 v2 = U4[f + 2 * stride];
        float4 v3 = U4[f + 3 * stride];
        accum(v0); accum(v1); accum(v2); accum(v3);
    }
    for (; f < nf4; f += stride)
        accum(U4[f]);

    red[tid] = acc;
    __syncthreads();

    if (tid < 64) {
        const int g = tid >> 2;   // float4-group covering output e = tid
        const int j = tid & 3;
        float s = 0.0f;
#pragma unroll
        for (int m = 0; m < 16; ++m) {
            const float* rp = reinterpret_cast<const float*>(&red[g + 16 * m]);
            s += rp[j];
        }
        __hip_atomic_store(&partial[blockIdx.x * 64 + tid], s,
                           __ATOMIC_RELAXED, __HIP_MEMORY_SCOPE_AGENT);
    }

    // barrier drains vmcnt(0): our partial stores are complete at the
    // coherent point before the counter bump below.
    __syncthreads();
    if (tid == 0) {
        int old = __hip_atomic_fetch_add(counter, 1, __ATOMIC_RELAXED,
                                         __HIP_MEMORY_SCOPE_AGENT);
        lastflag = (old == NBLK - 1);
    }
    __syncthreads();

    if (lastflag) {
        // thread t: e = t&63, row-group rg = t>>6; wave reads 64 consecutive
        // floats per iteration (coalesced 256B). Fixed order -> deterministic.
        const int e  = tid & 63;
        const int rg = tid >> 6;   // 0..3
        float s2 = 0.0f;
        for (int r = rg; r < NBLK; r += 4) {
            s2 += __hip_atomic_load(&partial[r * 64 + e],
                                    __ATOMIC_RELAXED, __HIP_MEMORY_SCOPE_AGENT);
        }
        float* redf = reinterpret_cast<float*>(red);
        redf[tid] = s2;
        __syncthreads();
        if (tid < 64) {
            float t4s = redf[tid] + redf[tid + 64] + redf[tid + 128] + redf[tid + 192];
            out[tid] = t4s * inv_n;
        }
    }
}

extern "C" void kernel_launch(void* const* d_in, const int* in_sizes, int n_in,
                              void* d_out, int out_size, void* d_ws, size_t ws_size,
                              hipStream_t stream) {
    const float* U  = (const float*)d_in[0];
    const float* W1 = (const float*)d_in[1];
    const float* b1 = (const float*)d_in[2];
    const float* W2 = (const float*)d_in[3];
    const float* b2 = (const float*)d_in[4];
    const float* W3 = (const float*)d_in[5];
    const float* b3 = (const float*)d_in[6];
    float* out = (float*)d_out;

    float* table   = (float*)d_ws;                       // 16 KiB
    float* partial = (float*)d_ws + TAB_N;               // NBLK*64 floats
    int*   counter = (int*)((float*)d_ws + TAB_N + NBLK * 64);

    const int total = in_sizes[0];     // N * 64
    const int n_rows = total / 64;     // N
    const int nf4 = total / 4;

    build_table_kernel<<<TAB_N / 16, 256, 0, stream>>>(
        W1, b1, W2, b2, W3, b3, table, counter);

    mlp_mean_kernel<<<NBLK, 256, 0, stream>>>(
        (const float4*)U, table, partial, counter, out, nf4,
        1.0f / (float)n_rows);
}

// Round 9
// 27.405 us; speedup vs baseline: 1.8258x; 1.8258x over previous
//
#include <hip/hip_runtime.h>

#define HH 128
#define TAB_N 4096
#define TAB_LO (-8.0f)
#define TAB_HI (8.0f)
#define NBLK 512

// ws layout: [0,16KB) table | [16KB,16KB+128KB) partial[NBLK][64] | counter

// ---------------------------------------------------------------------------
// Kernel A (register-resident W2): tabulate
//   y(u) = W3^T relu(W2^T relu(u*w1+b1) + b2) + b3
// on TAB_N uniform grid points, exact fp32. 256 blocks x 256 threads; block
// handles 16 consecutive entries. Thread (c = tid&31, ig = tid>>5) owns W2
// rows 16ig..16ig+15, cols 4c..4c+3 in registers. Phase 1 all-register FMA;
// phase 2 one LDS round trip + 16-lane shfl reduce -> table entry.
// Block 0 resets kernel B's completion counter via a write-through
// agent-scope store (ws is NOT re-zeroed between graph replays).
// ---------------------------------------------------------------------------
__global__ __launch_bounds__(256) void build_table_kernel(
    const float* __restrict__ W1, const float* __restrict__ b1,
    const float* __restrict__ W2, const float* __restrict__ b2,
    const float* __restrict__ W3, const float* __restrict__ b3,
    float* __restrict__ table, int* __restrict__ counter)
{
    __shared__ float4 lds4[16 * 8 * 32];  // [entry][ig][c] = 64 KiB
    const int tid = threadIdx.x;
    const int c  = tid & 31;   // col-group: cols 4c..4c+3
    const int ig = tid >> 5;   // row-group: rows 16ig..16ig+15

    if (blockIdx.x == 0 && tid == 0)
        __hip_atomic_store(counter, 0, __ATOMIC_RELAXED,
                           __HIP_MEMORY_SCOPE_AGENT);

    // --- load register tiles ---
    float4 w2r[16];
    const float4* W2v = reinterpret_cast<const float4*>(W2);
#pragma unroll
    for (int r = 0; r < 16; ++r)
        w2r[r] = W2v[(16 * ig + r) * 32 + c];   // W2[row][4c..4c+3]

    float w1r[16], b1r[16];
#pragma unroll
    for (int r = 0; r < 16; ++r) {
        w1r[r] = W1[16 * ig + r];
        b1r[r] = b1[16 * ig + r];
    }

    const float step = (TAB_HI - TAB_LO) / (float)(TAB_N - 1);
    const int e0 = blockIdx.x * 16;

    // --- phase 1: all-register FMA for the block's 16 entries ---
    float4 facc[16];
#pragma unroll
    for (int e = 0; e < 16; ++e) {
        const float u = TAB_LO + step * (float)(e0 + e);
        float4 a = make_float4(0.f, 0.f, 0.f, 0.f);
#pragma unroll
        for (int r = 0; r < 16; ++r) {
            const float h1 = fmaxf(fmaf(u, w1r[r], b1r[r]), 0.0f);
            a.x = fmaf(h1, w2r[r].x, a.x);
            a.y = fmaf(h1, w2r[r].y, a.y);
            a.z = fmaf(h1, w2r[r].z, a.z);
            a.w = fmaf(h1, w2r[r].w, a.w);
        }
        facc[e] = a;
    }

    // --- phase 2: single LDS round trip + reduce ---
#pragma unroll
    for (int e = 0; e < 16; ++e)
        lds4[(e * 8 + ig) * 32 + c] = facc[e];
    __syncthreads();

    // 512 (entry, col-group) cells; 2 per thread. cell = 2*tid+t:
    //   e = cell>>5 = tid>>4,  c2 = cell&31 = 2*(tid&15)+t
    const float4* b2v = reinterpret_cast<const float4*>(b2);
    const float4* W3v = reinterpret_cast<const float4*>(W3);
    float part = 0.0f;
#pragma unroll
    for (int t = 0; t < 2; ++t) {
        const int cell = 2 * tid + t;
        const int e  = cell >> 5;
        const int c2 = cell & 31;
        float4 s = make_float4(0.f, 0.f, 0.f, 0.f);
#pragma unroll
        for (int m = 0; m < 8; ++m) {
            const float4 v = lds4[(e * 8 + m) * 32 + c2];
            s.x += v.x; s.y += v.y; s.z += v.z; s.w += v.w;
        }
        const float4 bb = b2v[c2];
        const float4 ww = W3v[c2];
        float v = 0.0f;
        v += fmaxf(s.x + bb.x, 0.f) * ww.x;
        v += fmaxf(s.y + bb.y, 0.f) * ww.y;
        v += fmaxf(s.z + bb.z, 0.f) * ww.z;
        v += fmaxf(s.w + bb.w, 0.f) * ww.w;
        part += v;
    }
    part += __shfl_xor(part, 1, 16);
    part += __shfl_xor(part, 2, 16);
    part += __shfl_xor(part, 4, 16);
    part += __shfl_xor(part, 8, 16);
    if ((tid & 15) == 0)
        table[e0 + (tid >> 4)] = part + b3[0];
}

// ---------------------------------------------------------------------------
// Kernel B: stream U as float4 (unroll x4), nearest-neighbor y(u) from
// 16 KiB LDS table, block-reduce in LDS, publish 64 partials per block via
// agent-scope RELAXED ATOMIC STORES (write-through to the coherent point,
// fire-and-forget). __syncthreads() drains vmcnt(0) -> stores complete
// before the single per-block fetch_add. The fetch_add uses ACQUIRE
// ordering: the compiler emits the L1/L2 invalidate, so the last block's
// subsequent PLAIN float4 loads of partial[] (fully pipelined, coalesced)
// cannot hit stale L2 lines from a previous graph replay. Fixed-order
// reduce -> deterministic. No fp32 atomics, no threadfence, no atomic
// loads in loops.
// ---------------------------------------------------------------------------
__global__ __launch_bounds__(256) void mlp_mean_kernel(
    const float4* __restrict__ U4, const float* __restrict__ table,
    float* __restrict__ partial, int* __restrict__ counter,
    float* __restrict__ out, int nf4, float inv_n)
{
    __shared__ float tabs[TAB_N];   // 16 KiB
    __shared__ float4 red[256];     // 4 KiB (reused by the finalize)
    __shared__ int lastflag;
    const int tid = threadIdx.x;

    {
        const float4* tv = reinterpret_cast<const float4*>(table);
        float4* t4 = reinterpret_cast<float4*>(tabs);
#pragma unroll
        for (int j = 0; j < (TAB_N / 4) / 256; ++j)
            t4[tid + 256 * j] = tv[tid + 256 * j];
    }
    __syncthreads();

    const float step = (TAB_HI - TAB_LO) / (float)(TAB_N - 1);
    const float scale = 1.0f / step;
    const float bias = 0.5f - TAB_LO * scale;
    const float tmax = (float)(TAB_N - 1) + 0.49f;

    float4 acc = make_float4(0.f, 0.f, 0.f, 0.f);
    auto accum = [&](float4 v) {
        float t0 = fminf(fmaxf(fmaf(v.x, scale, bias), 0.f), tmax);
        float t1 = fminf(fmaxf(fmaf(v.y, scale, bias), 0.f), tmax);
        float t2 = fminf(fmaxf(fmaf(v.z, scale, bias), 0.f), tmax);
        float t3 = fminf(fmaxf(fmaf(v.w, scale, bias), 0.f), tmax);
        acc.x += tabs[(int)t0];
        acc.y += tabs[(int)t1];
        acc.z += tabs[(int)t2];
        acc.w += tabs[(int)t3];
    };

    const int stride = NBLK * 256;
    int f = blockIdx.x * 256 + tid;
    for (; f + 3 * stride < nf4; f += 4 * stride) {
        float4 v0 = U4[f];
        float4 v1 = U4[f + stride];
        float4 v2 = U4[f + 2 * stride];
        float4 v3 = U4[f + 3 * stride];
        accum(v0); accum(v1); accum(v2); accum(v3);
    }
    for (; f < nf4; f += stride)
        accum(U4[f]);

    red[tid] = acc;
    __syncthreads();

    if (tid < 64) {
        const int g = tid >> 2;   // float4-group covering output e = tid
        const int j = tid & 3;
        float s = 0.0f;
#pragma unroll
        for (int m = 0; m < 16; ++m) {
            const float* rp = reinterpret_cast<const float*>(&red[g + 16 * m]);
            s += rp[j];
        }
        __hip_atomic_store(&partial[blockIdx.x * 64 + tid], s,
                           __ATOMIC_RELAXED, __HIP_MEMORY_SCOPE_AGENT);
    }

    // barrier drains vmcnt(0): this block's partial stores have reached the
    // coherent point before the counter bump below.
    __syncthreads();
    if (tid == 0) {
        int old = __hip_atomic_fetch_add(counter, 1, __ATOMIC_ACQUIRE,
                                         __HIP_MEMORY_SCOPE_AGENT);
        lastflag = (old == NBLK - 1);
    }
    __syncthreads();

    if (lastflag) {
        // partial viewed as [NBLK][16] float4. Thread (q = tid&15,
        // rg = tid>>4) sums rows rg, rg+16, ... with dual accumulators
        // (independent plain loads -> pipelined), then LDS reduce over the
        // 16 row-groups. Fixed order -> bit-deterministic.
        const float4* p4 = reinterpret_cast<const float4*>(partial);
        const int q  = tid & 15;
        const int rg = tid >> 4;   // 0..15
        float4 s0 = make_float4(0.f, 0.f, 0.f, 0.f);
        float4 s1 = make_float4(0.f, 0.f, 0.f, 0.f);
        for (int r = rg; r < NBLK; r += 32) {
            float4 a = p4[r * 16 + q];
            float4 b = p4[(r + 16) * 16 + q];
            s0.x += a.x; s0.y += a.y; s0.z += a.z; s0.w += a.w;
            s1.x += b.x; s1.y += b.y; s1.z += b.z; s1.w += b.w;
        }
        float4 s;
        s.x = s0.x + s1.x; s.y = s0.y + s1.y;
        s.z = s0.z + s1.z; s.w = s0.w + s1.w;
        red[rg * 16 + q] = s;   // reuse red as [16 rg][16 q]
        __syncthreads();
        if (tid < 16) {
            float4 t = make_float4(0.f, 0.f, 0.f, 0.f);
#pragma unroll
            for (int m = 0; m < 16; ++m) {
                float4 v = red[m * 16 + tid];
                t.x += v.x; t.y += v.y; t.z += v.z; t.w += v.w;
            }
            out[tid * 4 + 0] = t.x * inv_n;
            out[tid * 4 + 1] = t.y * inv_n;
            out[tid * 4 + 2] = t.z * inv_n;
            out[tid * 4 + 3] = t.w * inv_n;
        }
    }
}

extern "C" void kernel_launch(void* const* d_in, const int* in_sizes, int n_in,
                              void* d_out, int out_size, void* d_ws, size_t ws_size,
                              hipStream_t stream) {
    const float* U  = (const float*)d_in[0];
    const float* W1 = (const float*)d_in[1];
    const float* b1 = (const float*)d_in[2];
    const float* W2 = (const float*)d_in[3];
    const float* b2 = (const float*)d_in[4];
    const float* W3 = (const float*)d_in[5];
    const float* b3 = (const float*)d_in[6];
    float* out = (float*)d_out;

    float* table   = (float*)d_ws;                       // 16 KiB
    float* partial = (float*)d_ws + TAB_N;               // NBLK*64 floats
    int*   counter = (int*)((float*)d_ws + TAB_N + NBLK * 64);

    const int total = in_sizes[0];     // N * 64
    const int n_rows = total / 64;     // N
    const int nf4 = total / 4;

    build_table_kernel<<<TAB_N / 16, 256, 0, stream>>>(
        W1, b1, W2, b2, W3, b3, table, counter);

    mlp_mean_kernel<<<NBLK, 256, 0, stream>>>(
        (const float4*)U, table, partial, counter, out, nf4,
        1.0f / (float)n_rows);
}

// Round 10
// 22.064 us; speedup vs baseline: 2.2678x; 1.2421x over previous
//
#include <hip/hip_runtime.h>

#define HH 128
#define TAB_N 4096
#define TAB_LO (-8.0f)
#define TAB_HI (8.0f)
#define NBLK 512

typedef float f32x4 __attribute__((ext_vector_type(4)));

// ws layout: [0,16KB) table | [16KB,16KB+128KB) partial[NBLK][64] | counter

// ---------------------------------------------------------------------------
// Kernel A (register-resident W2): tabulate
//   y(u) = W3^T relu(W2^T relu(u*w1+b1) + b2) + b3
// on TAB_N uniform grid points, exact fp32. 256 blocks x 256 threads; block
// handles 16 consecutive entries. Thread (c = tid&31, ig = tid>>5) owns W2
// rows 16ig..16ig+15, cols 4c..4c+3 in registers. Phase 1 all-register FMA;
// phase 2 one LDS round trip + 16-lane shfl reduce -> table entry.
// Block 0 resets kernel B's completion counter (relaxed agent store,
// write-through; ws is NOT re-zeroed between graph replays).
// ---------------------------------------------------------------------------
__global__ __launch_bounds__(256) void build_table_kernel(
    const float* __restrict__ W1, const float* __restrict__ b1,
    const float* __restrict__ W2, const float* __restrict__ b2,
    const float* __restrict__ W3, const float* __restrict__ b3,
    float* __restrict__ table, int* __restrict__ counter)
{
    __shared__ float4 lds4[16 * 8 * 32];  // [entry][ig][c] = 64 KiB
    const int tid = threadIdx.x;
    const int c  = tid & 31;   // col-group: cols 4c..4c+3
    const int ig = tid >> 5;   // row-group: rows 16ig..16ig+15

    if (blockIdx.x == 0 && tid == 0)
        __hip_atomic_store(counter, 0, __ATOMIC_RELAXED,
                           __HIP_MEMORY_SCOPE_AGENT);

    // --- load register tiles ---
    float4 w2r[16];
    const float4* W2v = reinterpret_cast<const float4*>(W2);
#pragma unroll
    for (int r = 0; r < 16; ++r)
        w2r[r] = W2v[(16 * ig + r) * 32 + c];   // W2[row][4c..4c+3]

    float w1r[16], b1r[16];
#pragma unroll
    for (int r = 0; r < 16; ++r) {
        w1r[r] = W1[16 * ig + r];
        b1r[r] = b1[16 * ig + r];
    }

    const float step = (TAB_HI - TAB_LO) / (float)(TAB_N - 1);
    const int e0 = blockIdx.x * 16;

    // --- phase 1: all-register FMA for the block's 16 entries ---
    float4 facc[16];
#pragma unroll
    for (int e = 0; e < 16; ++e) {
        const float u = TAB_LO + step * (float)(e0 + e);
        float4 a = make_float4(0.f, 0.f, 0.f, 0.f);
#pragma unroll
        for (int r = 0; r < 16; ++r) {
            const float h1 = fmaxf(fmaf(u, w1r[r], b1r[r]), 0.0f);
            a.x = fmaf(h1, w2r[r].x, a.x);
            a.y = fmaf(h1, w2r[r].y, a.y);
            a.z = fmaf(h1, w2r[r].z, a.z);
            a.w = fmaf(h1, w2r[r].w, a.w);
        }
        facc[e] = a;
    }

    // --- phase 2: single LDS round trip + reduce ---
#pragma unroll
    for (int e = 0; e < 16; ++e)
        lds4[(e * 8 + ig) * 32 + c] = facc[e];
    __syncthreads();

    // 512 (entry, col-group) cells; 2 per thread. cell = 2*tid+t:
    //   e = cell>>5 = tid>>4,  c2 = cell&31 = 2*(tid&15)+t
    const float4* b2v = reinterpret_cast<const float4*>(b2);
    const float4* W3v = reinterpret_cast<const float4*>(W3);
    float part = 0.0f;
#pragma unroll
    for (int t = 0; t < 2; ++t) {
        const int cell = 2 * tid + t;
        const int e  = cell >> 5;
        const int c2 = cell & 31;
        float4 s = make_float4(0.f, 0.f, 0.f, 0.f);
#pragma unroll
        for (int m = 0; m < 8; ++m) {
            const float4 v = lds4[(e * 8 + m) * 32 + c2];
            s.x += v.x; s.y += v.y; s.z += v.z; s.w += v.w;
        }
        const float4 bb = b2v[c2];
        const float4 ww = W3v[c2];
        float v = 0.0f;
        v += fmaxf(s.x + bb.x, 0.f) * ww.x;
        v += fmaxf(s.y + bb.y, 0.f) * ww.y;
        v += fmaxf(s.z + bb.z, 0.f) * ww.z;
        v += fmaxf(s.w + bb.w, 0.f) * ww.w;
        part += v;
    }
    part += __shfl_xor(part, 1, 16);
    part += __shfl_xor(part, 2, 16);
    part += __shfl_xor(part, 4, 16);
    part += __shfl_xor(part, 8, 16);
    if ((tid & 15) == 0)
        table[e0 + (tid >> 4)] = part + b3[0];
}

// coherent-point pipelined load: bypasses L1/L2 (sc0 sc1) but is an
// ordinary vmcnt-counted load -> multiple can be in flight, unlike
// compiler-serialized __hip_atomic_load.
#define CLOAD(dst, ptr)                                         \
    asm volatile("global_load_dwordx4 %0, %1, off sc0 sc1"      \
                 : "=v"(dst) : "v"(ptr))

// ---------------------------------------------------------------------------
// Kernel B: stream U as f32x4 (unroll x4), nearest-neighbor y(u) from the
// 16 KiB LDS table, block-reduce in LDS, publish 64 partials per block via
// relaxed agent atomic stores (write-through, fire-and-forget; proven cheap
// in R8/R9). __syncthreads() drains vmcnt(0) so the stores have reached the
// coherent point before the single RELAXED fetch_add per block (no acquire
// -> no per-block L2 invalidate, the R9 regression). The last block reads
// partial[] with sc0sc1 asm loads (coherent-point reads, fully pipelined,
// dataflow-tied to their s_waitcnt via "+v" operands), reduces in a FIXED
// order, and writes out[64]. Deterministic; no fences, no CAS, no per-block
// cache maintenance, no serialized atomic loads.
// ---------------------------------------------------------------------------
__global__ __launch_bounds__(256) void mlp_mean_kernel(
    const f32x4* __restrict__ U4, const float* __restrict__ table,
    float* __restrict__ partial, int* __restrict__ counter,
    float* __restrict__ out, int nf4, float inv_n)
{
    __shared__ float tabs[TAB_N];   // 16 KiB
    __shared__ f32x4 red[256];      // 4 KiB (reused by the finalize)
    __shared__ int lastflag;
    const int tid = threadIdx.x;

    {
        const f32x4* tv = reinterpret_cast<const f32x4*>(table);
        f32x4* t4 = reinterpret_cast<f32x4*>(tabs);
#pragma unroll
        for (int j = 0; j < (TAB_N / 4) / 256; ++j)
            t4[tid + 256 * j] = tv[tid + 256 * j];
    }
    __syncthreads();

    const float step = (TAB_HI - TAB_LO) / (float)(TAB_N - 1);
    const float scale = 1.0f / step;
    const float bias = 0.5f - TAB_LO * scale;
    const float tmax = (float)(TAB_N - 1) + 0.49f;

    f32x4 acc = {0.f, 0.f, 0.f, 0.f};
    auto accum = [&](f32x4 v) {
        float t0 = fminf(fmaxf(fmaf(v.x, scale, bias), 0.f), tmax);
        float t1 = fminf(fmaxf(fmaf(v.y, scale, bias), 0.f), tmax);
        float t2 = fminf(fmaxf(fmaf(v.z, scale, bias), 0.f), tmax);
        float t3 = fminf(fmaxf(fmaf(v.w, scale, bias), 0.f), tmax);
        acc.x += tabs[(int)t0];
        acc.y += tabs[(int)t1];
        acc.z += tabs[(int)t2];
        acc.w += tabs[(int)t3];
    };

    const int stride = NBLK * 256;
    int f = blockIdx.x * 256 + tid;
    for (; f + 3 * stride < nf4; f += 4 * stride) {
        f32x4 v0 = U4[f];
        f32x4 v1 = U4[f + stride];
        f32x4 v2 = U4[f + 2 * stride];
        f32x4 v3 = U4[f + 3 * stride];
        accum(v0); accum(v1); accum(v2); accum(v3);
    }
    for (; f < nf4; f += stride)
        accum(U4[f]);

    red[tid] = acc;
    __syncthreads();

    if (tid < 64) {
        const int g = tid >> 2;   // float4-group covering output e = tid
        const int j = tid & 3;
        float s = 0.0f;
#pragma unroll
        for (int m = 0; m < 16; ++m) {
            const float* rp = reinterpret_cast<const float*>(&red[g + 16 * m]);
            s += rp[j];
        }
        __hip_atomic_store(&partial[blockIdx.x * 64 + tid], s,
                           __ATOMIC_RELAXED, __HIP_MEMORY_SCOPE_AGENT);
    }

    // barrier drains vmcnt(0): this block's partial stores have reached the
    // coherent point before the counter bump below.
    __syncthreads();
    if (tid == 0) {
        int old = __hip_atomic_fetch_add(counter, 1, __ATOMIC_RELAXED,
                                         __HIP_MEMORY_SCOPE_AGENT);
        lastflag = (old == NBLK - 1);
    }
    __syncthreads();

    if (lastflag) {
        // partial viewed as [NBLK][16] f32x4. Thread (q = tid&15, rg =
        // tid>>4) owns rows rg, rg+16, ... (32 rows): 4 batches of 8
        // pipelined coherent loads, each batch tied to one s_waitcnt.
        // Fixed summation order -> bit-deterministic.
        const f32x4* p4 = reinterpret_cast<const f32x4*>(partial);
        const int q  = tid & 15;
        const int rg = tid >> 4;   // 0..15
        f32x4 s = {0.f, 0.f, 0.f, 0.f};
#pragma unroll
        for (int j = 0; j < 32; j += 8) {
            f32x4 v0, v1, v2, v3, v4, v5, v6, v7;
            CLOAD(v0, p4 + ((size_t)(rg + (j + 0) * 16) * 16 + q));
            CLOAD(v1, p4 + ((size_t)(rg + (j + 1) * 16) * 16 + q));
            CLOAD(v2, p4 + ((size_t)(rg + (j + 2) * 16) * 16 + q));
            CLOAD(v3, p4 + ((size_t)(rg + (j + 3) * 16) * 16 + q));
            CLOAD(v4, p4 + ((size_t)(rg + (j + 4) * 16) * 16 + q));
            CLOAD(v5, p4 + ((size_t)(rg + (j + 5) * 16) * 16 + q));
            CLOAD(v6, p4 + ((size_t)(rg + (j + 6) * 16) * 16 + q));
            CLOAD(v7, p4 + ((size_t)(rg + (j + 7) * 16) * 16 + q));
            asm volatile("s_waitcnt vmcnt(0)"
                         : "+v"(v0), "+v"(v1), "+v"(v2), "+v"(v3),
                           "+v"(v4), "+v"(v5), "+v"(v6), "+v"(v7));
            s += v0; s += v1; s += v2; s += v3;
            s += v4; s += v5; s += v6; s += v7;
        }
        red[rg * 16 + q] = s;   // reuse red as [16 rg][16 q]
        __syncthreads();
        if (tid < 16) {
            f32x4 t = {0.f, 0.f, 0.f, 0.f};
#pragma unroll
            for (int m = 0; m < 16; ++m)
                t += red[m * 16 + tid];
            out[tid * 4 + 0] = t.x * inv_n;
            out[tid * 4 + 1] = t.y * inv_n;
            out[tid * 4 + 2] = t.z * inv_n;
            out[tid * 4 + 3] = t.w * inv_n;
        }
    }
}

extern "C" void kernel_launch(void* const* d_in, const int* in_sizes, int n_in,
                              void* d_out, int out_size, void* d_ws, size_t ws_size,
                              hipStream_t stream) {
    const float* U  = (const float*)d_in[0];
    const float* W1 = (const float*)d_in[1];
    const float* b1 = (const float*)d_in[2];
    const float* W2 = (const float*)d_in[3];
    const float* b2 = (const float*)d_in[4];
    const float* W3 = (const float*)d_in[5];
    const float* b3 = (const float*)d_in[6];
    float* out = (float*)d_out;

    float* table   = (float*)d_ws;                       // 16 KiB
    float* partial = (float*)d_ws + TAB_N;               // NBLK*64 floats
    int*   counter = (int*)((float*)d_ws + TAB_N + NBLK * 64);

    const int total = in_sizes[0];     // N * 64
    const int n_rows = total / 64;     // N
    const int nf4 = total / 4;

    build_table_kernel<<<TAB_N / 16, 256, 0, stream>>>(
        W1, b1, W2, b2, W3, b3, table, counter);

    mlp_mean_kernel<<<NBLK, 256, 0, stream>>>(
        (const f32x4*)U, table, partial, counter, out, nf4,
        1.0f / (float)n_rows);
}